// Round 2
// baseline (400.283 us; speedup 1.0000x reference)
//
#include <hip/hip_runtime.h>

typedef __attribute__((ext_vector_type(8))) short bf16x8;
typedef __attribute__((ext_vector_type(4))) float f32x4;

#define DEV static __device__ __forceinline__

// ---- config ----
constexpr int DM   = 128;
constexpr int DIN  = 256;
constexpr int NP   = 65;      // NPATCH
constexpr int NSEQ = 512;     // B*C
constexpr int HNF  = 8320;    // DM*NP
constexpr int LOPL = NSEQ*HNF;   // shorts between hi and lo planes

// ---- ws layout (float offsets) ----
constexpr size_t OFF_FLAG = 0;
constexpr size_t OFF_MEAN = 16;                       // 512
constexpr size_t OFF_STD  = OFF_MEAN + 512;           // 512
constexpr size_t OFF_ANEG = OFF_STD  + 512;           // 2*256*16 = 8192
constexpr size_t OFF_CONVW= OFF_ANEG + 8192;          // 2048
constexpr size_t OFF_CONVB= OFF_CONVW+ 2048;          // 512
constexpr size_t OFF_DTPB = OFF_CONVB+ 512;           // 512
constexpr size_t OFF_DD   = OFF_DTPB + 512;           // 512
constexpr size_t OFF_PEWT = OFF_DD   + 512;           // 2048
constexpr size_t OFF_PEB  = OFF_PEWT + 2048;          // 128
constexpr size_t OFF_INF  = OFF_PEB  + 128;           // 131072 shorts = 65536 f
constexpr size_t OFF_XPF  = OFF_INF  + 65536;         // 24576 shorts = 12288 f
constexpr size_t OFF_OPF  = OFF_XPF  + 12288;         // 65536 shorts = 32768 f
constexpr size_t OFF_HDF  = OFF_OPF  + 32768;         // 798720 shorts = 399360 f
constexpr size_t OFF_PA   = OFF_HDF  + 399360;        // hi+lo planes: 2*NSEQ*HNF shorts
constexpr size_t OFF_PB   = OFF_PA   + (size_t)NSEQ*HNF; // (NSEQ*HNF floats per buffer)
// total = OFF_PB + NSEQ*HNF = 9,044,624 floats ~= 36.2 MB

DEV float b2f(unsigned short u){ union{unsigned v; float f;} x; x.v = ((unsigned)u)<<16; return x.f; }
DEV unsigned short f2b(float f){
  union{float f32; unsigned u;} x; x.f32 = f;
  unsigned r = x.u + 0x7fffu + ((x.u>>16)&1u);
  return (unsigned short)(r>>16);
}
DEV void split2(float v, unsigned short& h, unsigned short& l){
  h = f2b(v); l = f2b(v - b2f(h));
}
DEV float load_in(const void* p, size_t i, int isbf){
  return isbf ? b2f(((const unsigned short*)p)[i]) : ((const float*)p)[i];
}
DEV int detect_bf16(const void* x){
  const unsigned short* u = (const unsigned short*)x;
  int sane = 0;
  for (int i=0;i<128;i++){
    unsigned short v = u[2*i];
    int e = (v>>7)&0xff;
    if (v==0 || (e>=100 && e<=141)) sane++;
  }
  return sane >= 96;
}
DEV f32x4 mfma16(bf16x8 a, bf16x8 b, f32x4 c){
  return __builtin_amdgcn_mfma_f32_16x16x32_bf16(a,b,c,0,0,0);
}
DEV float sigm(float x){ return 1.f/(1.f+__expf(-x)); }
DEV float softplus(float x){ return fmaxf(x,0.f)+log1pf(__expf(-fabsf(x))); }

// =====================================================================
// prep: weights -> MFMA B-fragment order (exact bf16), small params fp32.
// frag[(tile)*512 + lane*8 + j] = W[n=nt*16+(lane&15)][k=kk*32+(lane>>4)*8+j]
// =====================================================================
__global__ void k_prep(const void* x_enc, const void* pe_w, const void* pe_b,
                       const void* in_w, const void* conv_w, const void* conv_b,
                       const void* xp_w, const void* dtp_b,
                       const void* A_log, const void* Dm, const void* op_w,
                       const void* head_w, float* __restrict__ ws)
{
  __shared__ int sflag;
  if (threadIdx.x==0) sflag = detect_bf16(x_enc);
  __syncthreads();
  const int isbf = sflag;
  if (blockIdx.x==0 && threadIdx.x==0) ws[OFF_FLAG] = (float)isbf;

  size_t i = (size_t)blockIdx.x*256 + threadIdx.x;
  const size_t nA=8192, nCW=2048, nCB=512, nDB=512, nD=512, nPW=2048, nPB=128;
  const size_t nIN=131072, nXP=24576, nOP=65536, nHD=798720;

  if (i < nA){ ws[OFF_ANEG+i] = -__expf(load_in(A_log,i,isbf)); return; } i -= nA;
  if (i < nCW){ ws[OFF_CONVW+i] = load_in(conv_w,i,isbf); return; } i -= nCW;
  if (i < nCB){ ws[OFF_CONVB+i] = load_in(conv_b,i,isbf); return; } i -= nCB;
  if (i < nDB){ ws[OFF_DTPB+i]  = load_in(dtp_b,i,isbf); return; } i -= nDB;
  if (i < nD){  ws[OFF_DD+i]    = load_in(Dm,i,isbf); return; } i -= nD;
  if (i < nPW){ size_t k=i>>7, dm=i&127; ws[OFF_PEWT+i]=load_in(pe_w, dm*16+k, isbf); return; } i -= nPW;
  if (i < nPB){ ws[OFF_PEB+i]   = load_in(pe_b,i,isbf); return; } i -= nPB;
  if (i < nIN){ // in_proj: B[k=d(128)][e(512)] = in_w[e][k], layout [l][nt32][kk4]
    size_t j=i&7, lane=(i>>3)&63, kk=(i>>9)&3, nt=(i>>11)&31, l=i>>16;
    size_t e=nt*16+(lane&15), k=kk*32+((lane>>4)*8)+j;
    ((unsigned short*)(ws+OFF_INF))[i] = f2b(load_in(in_w,(l*512+e)*128+k,isbf)); return;
  } i -= nIN;
  if (i < nXP){ // x_proj: B[k=d(256)][o(48 pad)] = xp_w[o][k], [l][nt3][kk8]
    size_t j=i&7, lane=(i>>3)&63, kk=(i>>9)&7; size_t rest=i>>12;
    size_t nt=rest%3, l=rest/3;
    size_t o=nt*16+(lane&15), k=kk*32+((lane>>4)*8)+j;
    float v = (o<40)? load_in(xp_w,(l*40+o)*256+k,isbf) : 0.f;
    ((unsigned short*)(ws+OFF_XPF))[i] = f2b(v); return;
  } i -= nXP;
  if (i < nOP){ // out_proj: B[k=d(256)][dm(128)] = op_w[dm][k], [l][nt8][kk8]
    size_t j=i&7, lane=(i>>3)&63, kk=(i>>9)&7, nt=(i>>12)&7, l=i>>15;
    size_t dm=nt*16+(lane&15), k=kk*32+((lane>>4)*8)+j;
    ((unsigned short*)(ws+OFF_OPF))[i] = f2b(load_in(op_w,(l*128+dm)*256+k,isbf)); return;
  } i -= nOP;
  if (i < nHD){ // head: B[k(8320)][pred(96)] = head_w[pred][k], [nt6][kk260]
    size_t j=i&7, lane=(i>>3)&63, t=i>>9;
    size_t kk=t%260, nt=t/260;
    size_t pr=nt*16+(lane&15), k=kk*32+((lane>>4)*8)+j;
    ((unsigned short*)(ws+OFF_HDF))[i] = f2b(load_in(head_w,pr*8320+k,isbf)); return;
  }
}

// =====================================================================
// RevIN stats + normalize + patch-embed conv -> PA (hi/lo bf16 planes)
// =====================================================================
__global__ void k_embed(const void* __restrict__ x_enc, float* __restrict__ ws)
{
  const int n = blockIdx.x, tid = threadIdx.x;
  const int b = n>>4, c = n&15;
  const int isbf = ws[OFF_FLAG] != 0.f;
  __shared__ float sx[512];
  __shared__ float spe[16*128];
  __shared__ float spb[128];
  __shared__ float rs[8], rq[8], sm[2];

  float v0 = load_in(x_enc, ((size_t)b*512+tid)*16 + c, isbf);
  float v1 = load_in(x_enc, ((size_t)b*512+tid+256)*16 + c, isbf);
  float s = v0+v1, q = v0*v0+v1*v1;
  for (int o=32;o;o>>=1){ s += __shfl_down(s,o,64); q += __shfl_down(q,o,64); }
  const int w = tid>>6, lane = tid&63;
  if (lane==0){ rs[w]=s; rq[w]=q; }
  __syncthreads();
  if (tid==0){
    float S=rs[0]+rs[1]+rs[2]+rs[3], Q=rq[0]+rq[1]+rq[2]+rq[3];
    float mean = S*(1.f/512.f);
    float var = fmaxf(Q*(1.f/512.f)-mean*mean, 0.f);
    float sd = sqrtf(var+1e-5f);
    sm[0]=mean; sm[1]=1.f/sd;
    ws[OFF_MEAN+n]=mean; ws[OFF_STD+n]=sd;
  }
  __syncthreads();
  const float mean=sm[0], rstd=sm[1];
  sx[tid]=(v0-mean)*rstd; sx[tid+256]=(v1-mean)*rstd;
  for (int i=tid;i<2048;i+=256) spe[i]=ws[OFF_PEWT+i];
  if (tid<128) spb[tid]=ws[OFF_PEB+tid];
  __syncthreads();

  unsigned short* pa_hi = (unsigned short*)(ws+OFF_PA);
  unsigned short* pa_lo = pa_hi + LOPL;
  for (int i=tid;i<NP*DM;i+=256){
    int t=i>>7, dm=i&127;
    float acc = spb[dm];
    int j0 = t*8-8;
    #pragma unroll
    for (int k=0;k<16;k++){ int j=j0+k; if ((unsigned)j<512u) acc += sx[j]*spe[k*128+dm]; }
    unsigned short h,lo2; split2(acc,h,lo2);
    pa_hi[(size_t)n*HNF+i] = h;
    pa_lo[(size_t)n*HNF+i] = lo2;
  }
}

// =====================================================================
// One fused Mamba layer, split-precision. block = one sequence.
// =====================================================================
__global__ __launch_bounds__(256,2)
void k_layer(int l, const unsigned short* __restrict__ pin,
             unsigned short* __restrict__ pout, float* __restrict__ ws,
             const void* __restrict__ dtp_w_raw)
{
  const int n = blockIdx.x, tid = threadIdx.x;
  const int w = tid>>6, lane = tid&63, ml = lane&15, quad = lane>>4;
  const int isbf = ws[OFF_FLAG] != 0.f;

  // LDS: s_hi [65][264] bf16 | s_lo [65][264] bf16 | s_dbc [65][40] f32
  __shared__ __align__(16) unsigned char arena[79040];
  unsigned short* s_hi = (unsigned short*)arena;
  unsigned short* s_lo = (unsigned short*)(arena+34320);
  float* s_dbc = (float*)(arena+68640);

  const unsigned short* INF = (const unsigned short*)(ws+OFF_INF) + (size_t)l*65536;
  const unsigned short* XPF = (const unsigned short*)(ws+OFF_XPF) + (size_t)l*12288;
  const unsigned short* OPF = (const unsigned short*)(ws+OFF_OPF) + (size_t)l*32768;
  const unsigned short* phi = pin + (size_t)n*HNF;
  const unsigned short* plo = phi + LOPL;

  // ---- phase 1: in_proj xin-half (M=65,N=256,K=128), split-A -> s_hi/s_lo
  for (int pass=0; pass<2; ++pass){
    f32x4 acc[5][2];
    #pragma unroll
    for (int mt=0;mt<5;mt++){
      #pragma unroll
      for (int p2=0;p2<2;p2++){ f32x4 z={0.f,0.f,0.f,0.f}; acc[mt][p2]=z; }
    }
    #pragma unroll
    for (int kk=0;kk<4;kk++){
      bf16x8 ah[5], al[5];
      #pragma unroll
      for (int mt=0;mt<5;mt++){
        int row = mt*16+ml; if (row>64) row=64;
        ah[mt] = *(const bf16x8*)&phi[(size_t)row*128 + kk*32 + quad*8];
        al[mt] = *(const bf16x8*)&plo[(size_t)row*128 + kk*32 + quad*8];
      }
      #pragma unroll
      for (int p2=0;p2<2;p2++){
        int nt = pass*8 + w*2 + p2;
        bf16x8 b = *(const bf16x8*)&INF[((size_t)(nt*4+kk))*512 + lane*8];
        #pragma unroll
        for (int mt=0;mt<5;mt++)
          acc[mt][p2] = mfma16(ah[mt],b,mfma16(al[mt],b,acc[mt][p2]));
      }
    }
    #pragma unroll
    for (int p2=0;p2<2;p2++){
      int e = (pass*8 + w*2 + p2)*16 + ml;
      #pragma unroll
      for (int mt=0;mt<5;mt++){
        #pragma unroll
        for (int r=0;r<4;r++){
          int t = mt*16+quad*4+r;
          if (t<NP){
            unsigned short h,lo2; split2(acc[mt][p2][r],h,lo2);
            s_hi[t*264+e]=h; s_lo[t*264+e]=lo2;
          }
        }
      }
    }
  }
  __syncthreads();

  // ---- phase 2: causal depthwise conv (k=4) + SiLU in place; thread=d
  {
    const int d = tid;
    const float4 wv = ((const float4*)(ws+OFF_CONVW))[l*256+d];
    const float bb = ws[OFF_CONVB + l*256+d];
    float x0=0.f,x1=0.f,x2=0.f;
    for (int t=0;t<NP;t++){
      float xi = b2f(s_hi[t*264+d]) + b2f(s_lo[t*264+d]);
      float v = bb + wv.x*x0 + wv.y*x1 + wv.z*x2 + wv.w*xi;
      x0=x1; x1=x2; x2=xi;
      float sv = v * sigm(v);
      unsigned short h,lo2; split2(sv,h,lo2);
      s_hi[t*264+d]=h; s_lo[t*264+d]=lo2;
    }
  }
  __syncthreads();

  // ---- phase 3: x_proj (M=65,N=48(40),K=256) split-A -> s_dbc fp32
  for (int tile=w; tile<15; tile+=4){
    int mt=tile/3, nt=tile%3;
    f32x4 acc={0.f,0.f,0.f,0.f};
    #pragma unroll
    for (int kk=0;kk<8;kk++){
      int row = mt*16+ml; if (row>64) row=64;
      bf16x8 ah = *(const bf16x8*)&s_hi[row*264 + kk*32 + quad*8];
      bf16x8 al = *(const bf16x8*)&s_lo[row*264 + kk*32 + quad*8];
      bf16x8 b  = *(const bf16x8*)&XPF[((size_t)(nt*8+kk))*512 + lane*8];
      acc = mfma16(ah,b,mfma16(al,b,acc));
    }
    int o = nt*16+ml;
    #pragma unroll
    for (int r=0;r<4;r++){
      int t=mt*16+quad*4+r;
      if (t<NP && o<40) s_dbc[t*40+o] = acc[r];
    }
  }
  __syncthreads();

  // ---- phase 4: dt (fp32, per-thread) + selective scan + D-skip; thread=d
  {
    const int d = tid;
    float A_[16];
    {
      const float4* ap = (const float4*)(ws+OFF_ANEG) + ((size_t)l*256+d)*4;
      #pragma unroll
      for (int qq=0;qq<4;qq++){ float4 t4 = ap[qq]; A_[qq*4]=t4.x; A_[qq*4+1]=t4.y; A_[qq*4+2]=t4.z; A_[qq*4+3]=t4.w; }
    }
    const float Dv = ws[OFF_DD + l*256+d];
    const float bias = ws[OFF_DTPB + l*256+d];
    float wdt[8];
    #pragma unroll
    for (int r=0;r<8;r++) wdt[r] = load_in(dtp_w_raw, ((size_t)l*256+d)*8+r, isbf);
    float h[16];
    #pragma unroll
    for (int ss=0;ss<16;ss++) h[ss]=0.f;
    for (int t=0;t<NP;t++){
      const float* row = &s_dbc[t*40];
      float4 q0 = *(const float4*)(row+0), q1 = *(const float4*)(row+4);
      float din = bias + q0.x*wdt[0]+q0.y*wdt[1]+q0.z*wdt[2]+q0.w*wdt[3]
                       + q1.x*wdt[4]+q1.y*wdt[5]+q1.z*wdt[6]+q1.w*wdt[7];
      float dtv = softplus(din);
      float xv = b2f(s_hi[t*264+d]) + b2f(s_lo[t*264+d]);
      float dtx = dtv*xv;
      float Bv[16], Cv[16];
      {
        float4 b0=*(const float4*)(row+8),  b1=*(const float4*)(row+12),
               b2v=*(const float4*)(row+16), b3=*(const float4*)(row+20);
        float4 c0=*(const float4*)(row+24), c1=*(const float4*)(row+28),
               c2=*(const float4*)(row+32), c3=*(const float4*)(row+36);
        Bv[0]=b0.x;Bv[1]=b0.y;Bv[2]=b0.z;Bv[3]=b0.w; Bv[4]=b1.x;Bv[5]=b1.y;Bv[6]=b1.z;Bv[7]=b1.w;
        Bv[8]=b2v.x;Bv[9]=b2v.y;Bv[10]=b2v.z;Bv[11]=b2v.w; Bv[12]=b3.x;Bv[13]=b3.y;Bv[14]=b3.z;Bv[15]=b3.w;
        Cv[0]=c0.x;Cv[1]=c0.y;Cv[2]=c0.z;Cv[3]=c0.w; Cv[4]=c1.x;Cv[5]=c1.y;Cv[6]=c1.z;Cv[7]=c1.w;
        Cv[8]=c2.x;Cv[9]=c2.y;Cv[10]=c2.z;Cv[11]=c2.w; Cv[12]=c3.x;Cv[13]=c3.y;Cv[14]=c3.z;Cv[15]=c3.w;
      }
      float y = 0.f;
      #pragma unroll
      for (int ss=0;ss<16;ss++){
        float dA = __expf(dtv*A_[ss]);
        h[ss] = dA*h[ss] + dtx*Bv[ss];
        y += h[ss]*Cv[ss];
      }
      float g0 = y + xv*Dv;
      unsigned short hh,lo2; split2(g0,hh,lo2);
      s_hi[t*264+d]=hh; s_lo[t*264+d]=lo2;
    }
  }
  __syncthreads();

  // ---- phase 5: z-half GEMM (recompute) + fused silu-gating in place
  for (int tile=w; tile<80; tile+=4){
    int mt=tile>>4, nt=tile&15;
    f32x4 acc={0.f,0.f,0.f,0.f};
    #pragma unroll
    for (int kk=0;kk<4;kk++){
      int row = mt*16+ml; if (row>64) row=64;
      bf16x8 ah = *(const bf16x8*)&phi[(size_t)row*128 + kk*32 + quad*8];
      bf16x8 al = *(const bf16x8*)&plo[(size_t)row*128 + kk*32 + quad*8];
      bf16x8 b  = *(const bf16x8*)&INF[((size_t)((16+nt)*4+kk))*512 + lane*8];
      acc = mfma16(ah,b,mfma16(al,b,acc));
    }
    int d = nt*16+ml;
    #pragma unroll
    for (int r=0;r<4;r++){
      int t = mt*16+quad*4+r;
      if (t<NP){
        float g0 = b2f(s_hi[t*264+d]) + b2f(s_lo[t*264+d]);
        float zv = acc[r];
        float g = g0 * zv * sigm(zv);
        unsigned short hh,lo2; split2(g,hh,lo2);
        s_hi[t*264+d]=hh; s_lo[t*264+d]=lo2;
      }
    }
  }
  __syncthreads();

  // ---- phase 6: out_proj (M=65,N=128,K=256) split-A -> pout planes
  {
    f32x4 acc[5][2];
    #pragma unroll
    for (int mt=0;mt<5;mt++){
      #pragma unroll
      for (int p2=0;p2<2;p2++){ f32x4 z={0.f,0.f,0.f,0.f}; acc[mt][p2]=z; }
    }
    #pragma unroll
    for (int kk=0;kk<8;kk++){
      bf16x8 ah[5], al[5];
      #pragma unroll
      for (int mt=0;mt<5;mt++){
        int row = mt*16+ml; if (row>64) row=64;
        ah[mt] = *(const bf16x8*)&s_hi[row*264 + kk*32 + quad*8];
        al[mt] = *(const bf16x8*)&s_lo[row*264 + kk*32 + quad*8];
      }
      #pragma unroll
      for (int p2=0;p2<2;p2++){
        bf16x8 b = *(const bf16x8*)&OPF[((size_t)((w*2+p2)*8+kk))*512 + lane*8];
        #pragma unroll
        for (int mt=0;mt<5;mt++)
          acc[mt][p2] = mfma16(ah[mt],b,mfma16(al[mt],b,acc[mt][p2]));
      }
    }
    #pragma unroll
    for (int p2=0;p2<2;p2++){
      int dm = (w*2+p2)*16+ml;
      #pragma unroll
      for (int mt=0;mt<5;mt++){
        #pragma unroll
        for (int r=0;r<4;r++){
          int t = mt*16+quad*4+r;
          if (t<NP){
            unsigned short hh,lo2; split2(acc[mt][p2][r],hh,lo2);
            pout[(size_t)n*HNF + t*128 + dm] = hh;
            pout[(size_t)n*HNF + t*128 + dm + LOPL] = lo2;
          }
        }
      }
    }
  }
}

// =====================================================================
// head GEMM (M=512,N=96,K=8320) split-A + de-norm.
// =====================================================================
__global__ void k_head(const float* __restrict__ ws, void* __restrict__ out)
{
  const int blk = blockIdx.x;
  const int nt = blk%6, mt = blk/6;
  const int tid = threadIdx.x, w = tid>>6, lane = tid&63, ml = lane&15, quad = lane>>4;
  const unsigned short* pa_hi = (const unsigned short*)(ws+OFF_PA);
  const unsigned short* pa_lo = pa_hi + LOPL;
  const unsigned short* HDF = (const unsigned short*)(ws+OFF_HDF);
  __shared__ float red[4][64][4];

  f32x4 acc={0.f,0.f,0.f,0.f};
  const size_t abase = (size_t)(mt*16+ml)*HNF + quad*8;
  for (int i=0;i<65;i++){
    int kk = w*65+i;
    bf16x8 ah = *(const bf16x8*)(pa_hi + abase + (size_t)kk*32);
    bf16x8 al = *(const bf16x8*)(pa_lo + abase + (size_t)kk*32);
    bf16x8 b = *(const bf16x8*)&HDF[((size_t)(nt*260+kk))*512 + lane*8];
    acc = mfma16(ah,b,mfma16(al,b,acc));
  }
  #pragma unroll
  for (int r=0;r<4;r++) red[w][lane][r]=acc[r];
  __syncthreads();
  if (w==0){
    const int isbf = ws[OFF_FLAG]!=0.f;
    #pragma unroll
    for (int r=0;r<4;r++){
      float s = red[0][lane][r]+red[1][lane][r]+red[2][lane][r]+red[3][lane][r];
      int nseq = mt*16 + quad*4 + r;
      int pred = nt*16 + ml;
      float val = s*ws[OFF_STD+nseq] + ws[OFF_MEAN+nseq];
      size_t o = ((size_t)(nseq>>4)*96 + pred)*16 + (nseq&15);
      if (isbf) ((unsigned short*)out)[o] = f2b(val);
      else      ((float*)out)[o] = val;
    }
  }
}

extern "C" void kernel_launch(void* const* d_in, const int* in_sizes, int n_in,
                              void* d_out, int out_size, void* d_ws, size_t ws_size,
                              hipStream_t stream)
{
  (void)in_sizes; (void)n_in; (void)out_size; (void)ws_size;
  float* ws = (float*)d_ws;
  const void* x_enc = d_in[0];
  const void* pe_w  = d_in[2];  const void* pe_b  = d_in[3];
  const void* in_w  = d_in[4];  const void* conv_w= d_in[5];
  const void* conv_b= d_in[6];  const void* xp_w  = d_in[7];
  const void* dtp_w = d_in[8];  const void* dtp_b = d_in[9];
  const void* A_log = d_in[10]; const void* Dm    = d_in[11];
  const void* op_w  = d_in[12]; const void* head_w= d_in[13];

  k_prep<<<4039,256,0,stream>>>(x_enc,pe_w,pe_b,in_w,conv_w,conv_b,xp_w,
                                dtp_b,A_log,Dm,op_w,head_w,ws);
  k_embed<<<NSEQ,256,0,stream>>>(x_enc,ws);
  unsigned short* pa = (unsigned short*)(ws+OFF_PA);
  unsigned short* pb = (unsigned short*)(ws+OFF_PB);
  k_layer<<<NSEQ,256,0,stream>>>(0,pa,pb,ws,dtp_w);
  k_layer<<<NSEQ,256,0,stream>>>(1,pb,pa,ws,dtp_w);
  k_head<<<192,256,0,stream>>>(ws,d_out);
}